// Round 4
// baseline (380.900 us; speedup 1.0000x reference)
//
#include <hip/hip_runtime.h>
#include <math.h>
#include <stdint.h>

#define BS 4
#define NE 48
#define DM 64
#define DR 64
#define N2 96   // 2*NE

typedef const __attribute__((address_space(1))) uint32_t* gptr_t;
typedef __attribute__((address_space(3))) uint32_t* lptr_t;

__device__ __forceinline__ float wsum(float v) {
#pragma unroll
    for (int m = 1; m < 64; m <<= 1) v += __shfl_xor(v, m, 64);
    return v;
}
__device__ __forceinline__ float wmax(float v) {
#pragma unroll
    for (int m = 1; m < 64; m <<= 1) v = fmaxf(v, __shfl_xor(v, m, 64));
    return v;
}

// One block per (b,i,j). 256 threads = 4 waves.
// Wave w handles k2 = w, w+4, w+8, ... (strided -> mask-balanced across waves).
__global__ __launch_bounds__(256, 3)
void hgnn_kernel(const float* __restrict__ ht,
                 const float* __restrict__ factor,
                 const float* __restrict__ W_c,
                 const float* __restrict__ b_c,
                 const float* __restrict__ v_w,
                 const float* __restrict__ W_fc,
                 const float* __restrict__ b_fc,
                 const float* __restrict__ ln_g,
                 const float* __restrict__ ln_b,
                 const int* __restrict__ ent_numbers,
                 float* __restrict__ out) {
    __shared__ float sTh[N2][DM];     // total_h rows for this (b,i,j): 24 KB
    __shared__ float sHt[DR];
    __shared__ float sE[N2];
    __shared__ float sA[N2];
    __shared__ float sPart[4][DM];
    __shared__ float sOut[DM];

    const int tid  = threadIdx.x;
    const int lane = tid & 63;
    const int wave = tid >> 6;

    // Bijective XCD swizzle: 9216 = 8 * 1152. All 48 sibling blocks of one
    // (b,i) slab land on the same XCD -> hb re-reads are L2-local.
    const int orig = blockIdx.x;
    const int bid  = (orig & 7) * (BS * NE * NE / 8) + (orig >> 3);

    const int b   = bid / (NE * NE);
    const int rem = bid - b * NE * NE;
    const int i   = rem / NE;
    const int j   = rem - i * NE;

    const int ent = ent_numbers[b];
    const bool row_valid = (i < ent) && (j < ent);

    // ---- stage total_h via global_load_lds (width 16):
    //      ha = factor[b,i,j,k,:]  -> sTh[0..47]
    //      hb = factor[b,i,k,j,:]  -> sTh[48..95]
    {
        const float* fbase = factor + (size_t)((b * NE + i) * NE + j) * NE * DM;
        const float4* srcA = (const float4*)fbase;
#pragma unroll
        for (int n = 0; n < 3; ++n) {
            const int idx0 = n * 256 + wave * 64;          // wave-uniform
            const float4* g = srcA + idx0 + lane;          // per-lane global
            __builtin_amdgcn_global_load_lds(
                (gptr_t)g,
                (lptr_t)((char*)&sTh[0][0] + (size_t)idx0 * 16),
                16, 0, 0);
        }
        const float* fb2 = factor + (size_t)(b * NE + i) * NE * NE * DM + (size_t)j * DM;
#pragma unroll
        for (int n = 0; n < 3; ++n) {
            const int idx0 = n * 256 + wave * 64;          // wave-uniform
            const int idx  = idx0 + lane;
            const int k    = idx >> 4;                     // 16 float4 per row
            const int r4   = idx & 15;
            const float4* g = (const float4*)(fb2 + (size_t)k * NE * DM) + r4;
            __builtin_amdgcn_global_load_lds(
                (gptr_t)g,
                (lptr_t)((char*)&sTh[0][0] + (size_t)(NE * 256) + (size_t)idx0 * 16),
                16, 0, 0);
        }
    }

    // ---- stage ht row (overlaps with DMA above) ----
    if (tid < DR) sHt[tid] = ht[((size_t)(b * NE + i) * NE + j) * DR + tid];

    // ---- register-cache W_c2 column for this lane (64 VGPRs); overlaps DMA ----
    float wcol[64];
#pragma unroll
    for (int r = 0; r < 64; ++r) wcol[r] = W_c[(size_t)(DM + r) * DM + lane];

    const float bc = b_c[lane];
    const float vw = v_w[lane];

    __syncthreads();   // drains vmcnt (global_load_lds) + lgkmcnt (sHt)

    // ---- htc[lane] = b_c + ht @ W_c[:64]  (computed redundantly per wave) ----
    float htc = bc;
    {
        const float4* htv = (const float4*)sHt;
#pragma unroll
        for (int r4 = 0; r4 < 16; ++r4) {
            float4 t = htv[r4];
            htc = fmaf(t.x, W_c[(4 * r4 + 0) * DM + lane], htc);
            htc = fmaf(t.y, W_c[(4 * r4 + 1) * DM + lane], htc);
            htc = fmaf(t.z, W_c[(4 * r4 + 2) * DM + lane], htc);
            htc = fmaf(t.w, W_c[(4 * r4 + 3) * DM + lane], htc);
        }
    }

    // ---- energy per k2, strided across waves (wave-uniform mask skip) ----
#pragma unroll 1
    for (int t = 0; t < 24; ++t) {
        const int k2 = 4 * t + wave;
        const int kk = (k2 >= NE) ? (k2 - NE) : k2;
        const bool masked = (kk == j) || !row_valid || (kk >= ent);
        if (masked) {
            if (lane == 0) sE[k2] = -10000.0f;
        } else {
            float a0 = 0.f, a1 = 0.f, a2 = 0.f, a3 = 0.f;
            const float4* thv = (const float4*)(&sTh[k2][0]);
#pragma unroll
            for (int r4 = 0; r4 < 16; ++r4) {
                float4 t4 = thv[r4];
                a0 = fmaf(t4.x, wcol[4 * r4 + 0], a0);
                a1 = fmaf(t4.y, wcol[4 * r4 + 1], a1);
                a2 = fmaf(t4.z, wcol[4 * r4 + 2], a2);
                a3 = fmaf(t4.w, wcol[4 * r4 + 3], a3);
            }
            float x = htc + ((a0 + a1) + (a2 + a3));
            float g = 0.5f * x * (1.0f + erff(x * 0.70710678118654752f));
            float e = wsum(g * vw);
            if (lane == 0) sE[k2] = e;
        }
    }
    __syncthreads();

    // ---- softmax over 96 (computed redundantly per wave; expf reused) ----
    float v0 = sE[lane];
    float v1 = (lane < 32) ? sE[64 + lane] : -3.0e38f;
    float mx = wmax(fmaxf(v0, v1));
    float e0 = expf(v0 - mx);
    float e1 = (lane < 32) ? expf(v1 - mx) : 0.0f;
    float sm = wsum(e0 + e1);
    float inv = 1.0f / sm;
    if (wave == 0) {
        sA[lane] = e0 * inv;
        if (lane < 32) sA[64 + lane] = e1 * inv;
    }
    __syncthreads();

    // ---- output einsum: out[d] = sum_k2 a[k2] * th[k2][d] (strided) ----
    {
        float acc = 0.0f;
#pragma unroll
        for (int t = 0; t < 24; ++t) {
            const int k2 = 4 * t + wave;
            acc = fmaf(sA[k2], sTh[k2][lane], acc);
        }
        sPart[wave][lane] = acc;
    }
    __syncthreads();
    if (tid < DM)
        sOut[tid] = sPart[0][tid] + sPart[1][tid] + sPart[2][tid] + sPart[3][tid];
    __syncthreads();

    // ---- fc + residual + layernorm (wave 0) ----
    if (wave == 0) {
        float acc = b_fc[lane] + sHt[lane];
        const float4* ov = (const float4*)sOut;
#pragma unroll
        for (int r4 = 0; r4 < 16; ++r4) {
            float4 t4 = ov[r4];
            acc = fmaf(t4.x, W_fc[(4 * r4 + 0) * DM + lane], acc);
            acc = fmaf(t4.y, W_fc[(4 * r4 + 1) * DM + lane], acc);
            acc = fmaf(t4.z, W_fc[(4 * r4 + 2) * DM + lane], acc);
            acc = fmaf(t4.w, W_fc[(4 * r4 + 3) * DM + lane], acc);
        }
        float mu  = wsum(acc) * (1.0f / 64.0f);
        float d   = acc - mu;
        float var = wsum(d * d) * (1.0f / 64.0f);
        float y   = ln_g[lane] * d * rsqrtf(var + 1e-6f) + ln_b[lane];
        out[((size_t)(b * NE + i) * NE + j) * DM + lane] = y;
    }
}

extern "C" void kernel_launch(void* const* d_in, const int* in_sizes, int n_in,
                              void* d_out, int out_size, void* d_ws, size_t ws_size,
                              hipStream_t stream) {
    const float* ht   = (const float*)d_in[0];
    const float* fac  = (const float*)d_in[1];
    const float* W_c  = (const float*)d_in[2];
    const float* b_c  = (const float*)d_in[3];
    const float* v_w  = (const float*)d_in[4];
    const float* W_fc = (const float*)d_in[5];
    const float* b_fc = (const float*)d_in[6];
    const float* ln_g = (const float*)d_in[7];
    const float* ln_b = (const float*)d_in[8];
    const int*   ent  = (const int*)d_in[9];
    float* out = (float*)d_out;

    dim3 grid(BS * NE * NE);
    hgnn_kernel<<<grid, 256, 0, stream>>>(ht, fac, W_c, b_c, v_w, W_fc, b_fc,
                                          ln_g, ln_b, ent, out);
}

// Round 6
// 340.794 us; speedup vs baseline: 1.1177x; 1.1177x over previous
//
#include <hip/hip_runtime.h>
#include <math.h>
#include <stdint.h>

#define BS 4
#define NE 48
#define DM 64
#define DR 64
#define N2 96   // 2*NE

typedef const __attribute__((address_space(1))) uint32_t* gptr_t;
typedef __attribute__((address_space(3))) uint32_t* lptr_t;

__device__ __forceinline__ float wsum(float v) {
#pragma unroll
    for (int m = 1; m < 64; m <<= 1) v += __shfl_xor(v, m, 64);
    return v;
}
__device__ __forceinline__ float wmax(float v) {
#pragma unroll
    for (int m = 1; m < 64; m <<= 1) v = fmaxf(v, __shfl_xor(v, m, 64));
    return v;
}

// Inline erf: Abramowitz-Stegun 7.1.26, |abs err| <= 1.5e-7, straight-line,
// no OCML call -> no call-site register pressure, no branches.
__device__ __forceinline__ float erf_approx(float x) {
    float ax = fabsf(x);
    float t  = __builtin_amdgcn_rcpf(fmaf(0.3275911f, ax, 1.0f));
    float p  = t * (0.254829592f +
               t * (-0.284496736f +
               t * (1.421413741f +
               t * (-1.453152027f +
               t * 1.061405429f))));
    float e  = __expf(-ax * ax);
    float r  = fmaf(-p, e, 1.0f);
    return copysignf(r, x);
}
__device__ __forceinline__ float gelu_exact(float x) {
    return 0.5f * x * (1.0f + erf_approx(x * 0.70710678118654752440f));
}

// One block per (b,i,j). 256 threads = 4 waves.
// Wave w handles k2 = w, w+4, w+8, ... (strided -> mask-balanced), two rows
// per iteration for ILP.
__global__ __launch_bounds__(256, 3)
void hgnn_kernel(const float* __restrict__ ht,
                 const float* __restrict__ factor,
                 const float* __restrict__ W_c,
                 const float* __restrict__ b_c,
                 const float* __restrict__ v_w,
                 const float* __restrict__ W_fc,
                 const float* __restrict__ b_fc,
                 const float* __restrict__ ln_g,
                 const float* __restrict__ ln_b,
                 const int* __restrict__ ent_numbers,
                 float* __restrict__ out) {
    __shared__ float sTh[N2][DM];     // total_h rows for this (b,i,j): 24 KB
    __shared__ float sHt[DR];
    __shared__ float sE[N2];
    __shared__ float sA[N2];
    __shared__ float sPart[4][DM];
    __shared__ float sOut[DM];

    const int tid  = threadIdx.x;
    const int lane = tid & 63;
    const int wave = tid >> 6;

    // Bijective XCD swizzle: 9216 = 8 * 1152. All 48 sibling blocks of one
    // (b,i) slab land on the same XCD -> hb re-reads are L2-local.
    const int orig = blockIdx.x;
    const int bid  = (orig & 7) * (BS * NE * NE / 8) + (orig >> 3);

    const int b   = bid / (NE * NE);
    const int rem = bid - b * NE * NE;
    const int i   = rem / NE;
    const int j   = rem - i * NE;

    const int ent = ent_numbers[b];
    const bool row_valid = (i < ent) && (j < ent);

    // ---- stage total_h via global_load_lds (width 16):
    //      ha = factor[b,i,j,k,:]  -> sTh[0..47]
    //      hb = factor[b,i,k,j,:]  -> sTh[48..95]
    {
        const float* fbase = factor + (size_t)((b * NE + i) * NE + j) * NE * DM;
        const float4* srcA = (const float4*)fbase;
#pragma unroll
        for (int n = 0; n < 3; ++n) {
            const int idx0 = n * 256 + wave * 64;          // wave-uniform
            const float4* g = srcA + idx0 + lane;          // per-lane global
            __builtin_amdgcn_global_load_lds(
                (gptr_t)g,
                (lptr_t)((char*)&sTh[0][0] + (size_t)idx0 * 16),
                16, 0, 0);
        }
        const float* fb2 = factor + (size_t)(b * NE + i) * NE * NE * DM + (size_t)j * DM;
#pragma unroll
        for (int n = 0; n < 3; ++n) {
            const int idx0 = n * 256 + wave * 64;          // wave-uniform
            const int idx  = idx0 + lane;
            const int k    = idx >> 4;                     // 16 float4 per row
            const int r4   = idx & 15;
            const float4* g = (const float4*)(fb2 + (size_t)k * NE * DM) + r4;
            __builtin_amdgcn_global_load_lds(
                (gptr_t)g,
                (lptr_t)((char*)&sTh[0][0] + (size_t)(NE * 256) + (size_t)idx0 * 16),
                16, 0, 0);
        }
    }

    // ---- stage ht row (overlaps with DMA above) ----
    if (tid < DR) sHt[tid] = ht[((size_t)(b * NE + i) * NE + j) * DR + tid];

    // ---- register-cache W_c2 column for this lane; PIN into VGPRs so the
    //      compiler can neither rematerialize the loads nor spill ----
    float wcol[64];
#pragma unroll
    for (int r = 0; r < 64; ++r) wcol[r] = W_c[(size_t)(DM + r) * DM + lane];
#pragma unroll
    for (int r = 0; r < 64; ++r) asm volatile("" : "+v"(wcol[r]));

    const float bc = b_c[lane];
    const float vw = v_w[lane];

    __syncthreads();   // drains vmcnt (global_load_lds) + lgkmcnt (sHt)

    // ---- htc[lane] = b_c + ht @ W_c[:64]  (computed redundantly per wave) ----
    float htc = bc;
    {
        const float4* htv = (const float4*)sHt;
#pragma unroll
        for (int r4 = 0; r4 < 16; ++r4) {
            float4 t = htv[r4];
            htc = fmaf(t.x, W_c[(4 * r4 + 0) * DM + lane], htc);
            htc = fmaf(t.y, W_c[(4 * r4 + 1) * DM + lane], htc);
            htc = fmaf(t.z, W_c[(4 * r4 + 2) * DM + lane], htc);
            htc = fmaf(t.w, W_c[(4 * r4 + 3) * DM + lane], htc);
        }
    }

    // ---- energy: two k2 rows per iteration (ILP), strided across waves ----
#pragma unroll 1
    for (int t = 0; t < 12; ++t) {
        const int k2a = 8 * t + wave;
        const int k2b = k2a + 4;
        const int ka  = (k2a >= NE) ? (k2a - NE) : k2a;
        const int kb  = (k2b >= NE) ? (k2b - NE) : k2b;
        const bool va = row_valid && (ka != j) && (ka < ent);
        const bool vb = row_valid && (kb != j) && (kb < ent);
        if (!va && !vb) {
            if (lane == 0) { sE[k2a] = -10000.0f; sE[k2b] = -10000.0f; }
            continue;
        }
        float a0 = 0.f, a1 = 0.f, a2 = 0.f, a3 = 0.f;
        float b0 = 0.f, b1 = 0.f, b2 = 0.f, b3 = 0.f;
        const float4* ra = (const float4*)(&sTh[k2a][0]);
        const float4* rb = (const float4*)(&sTh[k2b][0]);
#pragma unroll
        for (int r4 = 0; r4 < 16; ++r4) {
            float4 ta = ra[r4];
            float4 tb = rb[r4];
            a0 = fmaf(ta.x, wcol[4 * r4 + 0], a0);
            b0 = fmaf(tb.x, wcol[4 * r4 + 0], b0);
            a1 = fmaf(ta.y, wcol[4 * r4 + 1], a1);
            b1 = fmaf(tb.y, wcol[4 * r4 + 1], b1);
            a2 = fmaf(ta.z, wcol[4 * r4 + 2], a2);
            b2 = fmaf(tb.z, wcol[4 * r4 + 2], b2);
            a3 = fmaf(ta.w, wcol[4 * r4 + 3], a3);
            b3 = fmaf(tb.w, wcol[4 * r4 + 3], b3);
        }
        float xa = htc + ((a0 + a1) + (a2 + a3));
        float xb = htc + ((b0 + b1) + (b2 + b3));
        float ea = wsum(gelu_exact(xa) * vw);
        float eb = wsum(gelu_exact(xb) * vw);
        if (lane == 0) {
            sE[k2a] = va ? ea : -10000.0f;
            sE[k2b] = vb ? eb : -10000.0f;
        }
    }
    __syncthreads();

    // ---- softmax over 96 (computed redundantly per wave; expf reused) ----
    float v0 = sE[lane];
    float v1 = (lane < 32) ? sE[64 + lane] : -3.0e38f;
    float mx = wmax(fmaxf(v0, v1));
    float e0 = expf(v0 - mx);
    float e1 = (lane < 32) ? expf(v1 - mx) : 0.0f;
    float sm = wsum(e0 + e1);
    float inv = 1.0f / sm;
    if (wave == 0) {
        sA[lane] = e0 * inv;
        if (lane < 32) sA[64 + lane] = e1 * inv;
    }
    __syncthreads();

    // ---- output einsum: out[d] = sum_k2 a[k2] * th[k2][d] (strided) ----
    {
        float acc = 0.0f;
#pragma unroll
        for (int t = 0; t < 24; ++t) {
            const int k2 = 4 * t + wave;
            acc = fmaf(sA[k2], sTh[k2][lane], acc);
        }
        sPart[wave][lane] = acc;
    }
    __syncthreads();
    if (tid < DM)
        sOut[tid] = sPart[0][tid] + sPart[1][tid] + sPart[2][tid] + sPart[3][tid];
    __syncthreads();

    // ---- fc + residual + layernorm (wave 0) ----
    if (wave == 0) {
        float acc = b_fc[lane] + sHt[lane];
        const float4* ov = (const float4*)sOut;
#pragma unroll
        for (int r4 = 0; r4 < 16; ++r4) {
            float4 t4 = ov[r4];
            acc = fmaf(t4.x, W_fc[(4 * r4 + 0) * DM + lane], acc);
            acc = fmaf(t4.y, W_fc[(4 * r4 + 1) * DM + lane], acc);
            acc = fmaf(t4.z, W_fc[(4 * r4 + 2) * DM + lane], acc);
            acc = fmaf(t4.w, W_fc[(4 * r4 + 3) * DM + lane], acc);
        }
        float mu  = wsum(acc) * (1.0f / 64.0f);
        float d   = acc - mu;
        float var = wsum(d * d) * (1.0f / 64.0f);
        float y   = ln_g[lane] * d * rsqrtf(var + 1e-6f) + ln_b[lane];
        out[((size_t)(b * NE + i) * NE + j) * DM + lane] = y;
    }
}

extern "C" void kernel_launch(void* const* d_in, const int* in_sizes, int n_in,
                              void* d_out, int out_size, void* d_ws, size_t ws_size,
                              hipStream_t stream) {
    const float* ht   = (const float*)d_in[0];
    const float* fac  = (const float*)d_in[1];
    const float* W_c  = (const float*)d_in[2];
    const float* b_c  = (const float*)d_in[3];
    const float* v_w  = (const float*)d_in[4];
    const float* W_fc = (const float*)d_in[5];
    const float* b_fc = (const float*)d_in[6];
    const float* ln_g = (const float*)d_in[7];
    const float* ln_b = (const float*)d_in[8];
    const int*   ent  = (const int*)d_in[9];
    float* out = (float*)d_out;

    dim3 grid(BS * NE * NE);
    hgnn_kernel<<<grid, 256, 0, stream>>>(ht, fac, W_c, b_c, v_w, W_fc, b_fc,
                                          ln_g, ln_b, ent, out);
}

// Round 11
// 329.390 us; speedup vs baseline: 1.1564x; 1.0346x over previous
//
#include <hip/hip_runtime.h>
#include <math.h>
#include <stdint.h>

#define BS 4
#define NE 48
#define DM 64
#define DR 64
#define N2 96   // 2*NE

typedef const __attribute__((address_space(1))) uint32_t* gptr_t;
typedef __attribute__((address_space(3))) uint32_t* lptr_t;

__device__ __forceinline__ float wsum(float v) {
#pragma unroll
    for (int m = 1; m < 64; m <<= 1) v += __shfl_xor(v, m, 64);
    return v;
}
__device__ __forceinline__ float wmax(float v) {
#pragma unroll
    for (int m = 1; m < 64; m <<= 1) v = fmaxf(v, __shfl_xor(v, m, 64));
    return v;
}

// Inline erf: Abramowitz-Stegun 7.1.26, |abs err| <= 1.5e-7, straight-line,
// no OCML call, no branches.
__device__ __forceinline__ float erf_approx(float x) {
    float ax = fabsf(x);
    float t  = __builtin_amdgcn_rcpf(fmaf(0.3275911f, ax, 1.0f));
    float p  = t * (0.254829592f +
               t * (-0.284496736f +
               t * (1.421413741f +
               t * (-1.453152027f +
               t * 1.061405429f))));
    float e  = __expf(-ax * ax);
    float r  = fmaf(-p, e, 1.0f);
    return copysignf(r, x);
}
__device__ __forceinline__ float gelu_exact(float x) {
    return 0.5f * x * (1.0f + erf_approx(x * 0.70710678118654752440f));
}

// One block per (b,i,j). 256 threads = 4 waves.
// Wave w handles k2 = w, w+4, ... (strided, mask-balanced), FOUR rows per
// iteration: each W value is fetched once and used 4x, and the 4 independent
// shuffle-reduce chains interleave to hide ds_bpermute latency.
// launch_bounds(256,4): VGPR cap 128 -- enough for wcol[64]+4-row temps
// (~110) without spill; bound 5 would cap at ~102 and spill wcol.
__global__ __launch_bounds__(256, 4)
void hgnn_kernel(const float* __restrict__ ht,
                 const float* __restrict__ factor,
                 const float* __restrict__ W_c,
                 const float* __restrict__ b_c,
                 const float* __restrict__ v_w,
                 const float* __restrict__ W_fc,
                 const float* __restrict__ b_fc,
                 const float* __restrict__ ln_g,
                 const float* __restrict__ ln_b,
                 const int* __restrict__ ent_numbers,
                 float* __restrict__ out) {
    __shared__ float sTh[N2][DM];     // total_h rows for this (b,i,j): 24 KB
    __shared__ float sHt[DR];
    __shared__ float sE[N2];
    __shared__ float sA[N2];
    __shared__ float sPart[4][DM];
    __shared__ float sOut[DM];

    const int tid  = threadIdx.x;
    const int lane = tid & 63;
    const int wave = tid >> 6;

    // Bijective XCD swizzle: 9216 = 8 * 1152. All 48 sibling blocks of one
    // (b,i) slab land on the same XCD -> hb re-reads are L2-local.
    const int orig = blockIdx.x;
    const int bid  = (orig & 7) * (BS * NE * NE / 8) + (orig >> 3);

    const int b   = bid / (NE * NE);
    const int rem = bid - b * NE * NE;
    const int i   = rem / NE;
    const int j   = rem - i * NE;

    const int ent = ent_numbers[b];
    const bool row_valid = (i < ent) && (j < ent);

    // ---- stage total_h via global_load_lds (width 16):
    //      ha = factor[b,i,j,k,:]  -> sTh[0..47]
    //      hb = factor[b,i,k,j,:]  -> sTh[48..95]
    {
        const float* fbase = factor + (size_t)((b * NE + i) * NE + j) * NE * DM;
        const float4* srcA = (const float4*)fbase;
#pragma unroll
        for (int n = 0; n < 3; ++n) {
            const int idx0 = n * 256 + wave * 64;          // wave-uniform
            const float4* g = srcA + idx0 + lane;          // per-lane global
            __builtin_amdgcn_global_load_lds(
                (gptr_t)g,
                (lptr_t)((char*)&sTh[0][0] + (size_t)idx0 * 16),
                16, 0, 0);
        }
        const float* fb2 = factor + (size_t)(b * NE + i) * NE * NE * DM + (size_t)j * DM;
#pragma unroll
        for (int n = 0; n < 3; ++n) {
            const int idx0 = n * 256 + wave * 64;          // wave-uniform
            const int idx  = idx0 + lane;
            const int k    = idx >> 4;                     // 16 float4 per row
            const int r4   = idx & 15;
            const float4* g = (const float4*)(fb2 + (size_t)k * NE * DM) + r4;
            __builtin_amdgcn_global_load_lds(
                (gptr_t)g,
                (lptr_t)((char*)&sTh[0][0] + (size_t)(NE * 256) + (size_t)idx0 * 16),
                16, 0, 0);
        }
    }

    // ---- stage ht row (overlaps with DMA above) ----
    if (tid < DR) sHt[tid] = ht[((size_t)(b * NE + i) * NE + j) * DR + tid];

    // ---- W_c2 column for this lane (compiler's choice of residency; 4x
    //      reuse per fetch in the energy loop amortizes either way) ----
    float wcol[64];
#pragma unroll
    for (int r = 0; r < 64; ++r) wcol[r] = W_c[(size_t)(DM + r) * DM + lane];

    const float bc = b_c[lane];
    const float vw = v_w[lane];

    __syncthreads();   // drains vmcnt (global_load_lds) + lgkmcnt (sHt)

    // ---- htc[lane] = b_c + ht @ W_c[:64]  (computed redundantly per wave) ----
    float htc = bc;
    {
        const float4* htv = (const float4*)sHt;
#pragma unroll
        for (int r4 = 0; r4 < 16; ++r4) {
            float4 t = htv[r4];
            htc = fmaf(t.x, W_c[(4 * r4 + 0) * DM + lane], htc);
            htc = fmaf(t.y, W_c[(4 * r4 + 1) * DM + lane], htc);
            htc = fmaf(t.z, W_c[(4 * r4 + 2) * DM + lane], htc);
            htc = fmaf(t.w, W_c[(4 * r4 + 3) * DM + lane], htc);
        }
    }

    // ---- energy: FOUR k2 rows per iteration, strided across waves ----
#pragma unroll 1
    for (int t = 0; t < 6; ++t) {
        const int k0 = 16 * t + wave;   // rows k0, k0+4, k0+8, k0+12
        bool v[4];
#pragma unroll
        for (int q = 0; q < 4; ++q) {
            const int k2 = k0 + 4 * q;
            const int kk = (k2 >= NE) ? (k2 - NE) : k2;
            v[q] = row_valid && (kk != j) && (kk < ent);
        }
        if (!(v[0] | v[1] | v[2] | v[3])) {
            if (lane == 0) {
                sE[k0]      = -10000.0f;
                sE[k0 + 4]  = -10000.0f;
                sE[k0 + 8]  = -10000.0f;
                sE[k0 + 12] = -10000.0f;
            }
            continue;
        }
        float ac0 = 0.f, ac1 = 0.f, ac2 = 0.f, ac3 = 0.f;
        const float4* r0 = (const float4*)(&sTh[k0][0]);
        const float4* r1 = (const float4*)(&sTh[k0 + 4][0]);
        const float4* r2 = (const float4*)(&sTh[k0 + 8][0]);
        const float4* r3 = (const float4*)(&sTh[k0 + 12][0]);
#pragma unroll
        for (int r4 = 0; r4 < 16; ++r4) {
            float4 t0 = r0[r4];
            float4 t1 = r1[r4];
            float4 t2 = r2[r4];
            float4 t3 = r3[r4];
            float w0 = wcol[4 * r4 + 0];
            ac0 = fmaf(t0.x, w0, ac0); ac1 = fmaf(t1.x, w0, ac1);
            ac2 = fmaf(t2.x, w0, ac2); ac3 = fmaf(t3.x, w0, ac3);
            float w1 = wcol[4 * r4 + 1];
            ac0 = fmaf(t0.y, w1, ac0); ac1 = fmaf(t1.y, w1, ac1);
            ac2 = fmaf(t2.y, w1, ac2); ac3 = fmaf(t3.y, w1, ac3);
            float w2 = wcol[4 * r4 + 2];
            ac0 = fmaf(t0.z, w2, ac0); ac1 = fmaf(t1.z, w2, ac1);
            ac2 = fmaf(t2.z, w2, ac2); ac3 = fmaf(t3.z, w2, ac3);
            float w3 = wcol[4 * r4 + 3];
            ac0 = fmaf(t0.w, w3, ac0); ac1 = fmaf(t1.w, w3, ac1);
            ac2 = fmaf(t2.w, w3, ac2); ac3 = fmaf(t3.w, w3, ac3);
        }
        float s0 = gelu_exact(htc + ac0) * vw;
        float s1 = gelu_exact(htc + ac1) * vw;
        float s2 = gelu_exact(htc + ac2) * vw;
        float s3 = gelu_exact(htc + ac3) * vw;
        // 4 interleaved independent shuffle-reduce chains
#pragma unroll
        for (int m = 1; m < 64; m <<= 1) {
            float u0 = __shfl_xor(s0, m, 64);
            float u1 = __shfl_xor(s1, m, 64);
            float u2 = __shfl_xor(s2, m, 64);
            float u3 = __shfl_xor(s3, m, 64);
            s0 += u0; s1 += u1; s2 += u2; s3 += u3;
        }
        if (lane == 0) {
            sE[k0]      = v[0] ? s0 : -10000.0f;
            sE[k0 + 4]  = v[1] ? s1 : -10000.0f;
            sE[k0 + 8]  = v[2] ? s2 : -10000.0f;
            sE[k0 + 12] = v[3] ? s3 : -10000.0f;
        }
    }
    __syncthreads();

    // ---- softmax over 96 (computed redundantly per wave; __expf reused) ----
    float v0 = sE[lane];
    float v1 = (lane < 32) ? sE[64 + lane] : -3.0e38f;
    float mx = wmax(fmaxf(v0, v1));
    float e0 = __expf(v0 - mx);
    float e1 = (lane < 32) ? __expf(v1 - mx) : 0.0f;
    float sm = wsum(e0 + e1);
    float inv = 1.0f / sm;
    if (wave == 0) {
        sA[lane] = e0 * inv;
        if (lane < 32) sA[64 + lane] = e1 * inv;
    }
    __syncthreads();

    // ---- output einsum: out[d] = sum_k2 a[k2] * th[k2][d] (strided) ----
    {
        float acc = 0.0f;
#pragma unroll
        for (int t = 0; t < 24; ++t) {
            const int k2 = 4 * t + wave;
            acc = fmaf(sA[k2], sTh[k2][lane], acc);
        }
        sPart[wave][lane] = acc;
    }
    __syncthreads();
    if (tid < DM)
        sOut[tid] = sPart[0][tid] + sPart[1][tid] + sPart[2][tid] + sPart[3][tid];
    __syncthreads();

    // ---- fc + residual + layernorm (wave 0) ----
    if (wave == 0) {
        float acc = b_fc[lane] + sHt[lane];
        const float4* ov = (const float4*)sOut;
#pragma unroll
        for (int r4 = 0; r4 < 16; ++r4) {
            float4 t4 = ov[r4];
            acc = fmaf(t4.x, W_fc[(4 * r4 + 0) * DM + lane], acc);
            acc = fmaf(t4.y, W_fc[(4 * r4 + 1) * DM + lane], acc);
            acc = fmaf(t4.z, W_fc[(4 * r4 + 2) * DM + lane], acc);
            acc = fmaf(t4.w, W_fc[(4 * r4 + 3) * DM + lane], acc);
        }
        float mu  = wsum(acc) * (1.0f / 64.0f);
        float d   = acc - mu;
        float var = wsum(d * d) * (1.0f / 64.0f);
        float y   = ln_g[lane] * d * rsqrtf(var + 1e-6f) + ln_b[lane];
        out[((size_t)(b * NE + i) * NE + j) * DM + lane] = y;
    }
}

extern "C" void kernel_launch(void* const* d_in, const int* in_sizes, int n_in,
                              void* d_out, int out_size, void* d_ws, size_t ws_size,
                              hipStream_t stream) {
    const float* ht   = (const float*)d_in[0];
    const float* fac  = (const float*)d_in[1];
    const float* W_c  = (const float*)d_in[2];
    const float* b_c  = (const float*)d_in[3];
    const float* v_w  = (const float*)d_in[4];
    const float* W_fc = (const float*)d_in[5];
    const float* b_fc = (const float*)d_in[6];
    const float* ln_g = (const float*)d_in[7];
    const float* ln_b = (const float*)d_in[8];
    const int*   ent  = (const int*)d_in[9];
    float* out = (float*)d_out;

    dim3 grid(BS * NE * NE);
    hgnn_kernel<<<grid, 256, 0, stream>>>(ht, fac, W_c, b_c, v_w, W_fc, b_fc,
                                          ln_g, ln_b, ent, out);
}